// Round 5
// baseline (524.847 us; speedup 1.0000x reference)
//
#include <hip/hip_runtime.h>
#include <math.h>

// Biased grouped top-k MoE router (DeepSeek-V3 style).
// Outputs (concatenated flat in d_out, all written as float32):
//   [0,              T*8)        topk_weights
//   [T*8,            2*T*8)      topk_ids (stored as float values; ints <=255 exact)
//   [2*T*8,          2*T*8+T*E)  router_logits passthrough
//
// One wave64 per row of 256 experts: lane l owns experts [4l, 4l+4).

constexpr int E          = 256;
constexpr int TOPK       = 8;
constexpr int TOPK_GROUP = 4;
constexpr float SCALE    = 2.5f;

__global__ __launch_bounds__(256) void router_topk_kernel(
    const float* __restrict__ logits,   // [T, 256]
    const float* __restrict__ bias,     // [256]
    float* __restrict__ out_w,          // [T*8]
    float* __restrict__ out_id,         // [T*8] (float-encoded ids)
    float* __restrict__ out_lg,         // [T*256]
    int T)
{
    const int gtid = blockIdx.x * blockDim.x + threadIdx.x;
    const int row  = gtid >> 6;
    const int lane = threadIdx.x & 63;
    if (row >= T) return;

    // Coalesced float4 load: lane l reads experts 4l..4l+3 (1 KiB per wave).
    const float4 lg = *reinterpret_cast<const float4*>(logits + (size_t)row * E + lane * 4);
    const float4 bv = *reinterpret_cast<const float4*>(bias + lane * 4);

    // Passthrough copy of router_logits (exact).
    *reinterpret_cast<float4*>(out_lg + (size_t)row * E + lane * 4) = lg;

    float lgv[4] = {lg.x, lg.y, lg.z, lg.w};
    float bb[4]  = {bv.x, bv.y, bv.z, bv.w};
    float sc[4], sb[4];
    #pragma unroll
    for (int j = 0; j < 4; ++j) {
        sc[j] = 1.0f / (1.0f + expf(-lgv[j]));  // unbiased sigmoid score
        sb[j] = sc[j] + bb[j];                  // biased score (for selection)
    }

    // ---- per-group score: sum of top-2 biased scores within the group ----
    // Local top-2 of this lane's 4 values.
    float m1 = -INFINITY, m2 = -INFINITY;
    #pragma unroll
    for (int j = 0; j < 4; ++j) {
        float v = sb[j];
        if (v > m1)      { m2 = m1; m1 = v; }
        else if (v > m2) { m2 = v; }
    }
    // Merge top-2 pairs across the 8 lanes of this group (xor 1,2,4 stays
    // inside the 8-lane-aligned group; disjoint-subset merge is exact).
    #pragma unroll
    for (int d = 1; d < 8; d <<= 1) {
        float o1 = __shfl_xor(m1, d);
        float o2 = __shfl_xor(m2, d);
        float hi = fmaxf(m1, o1);
        float lo = fminf(m1, o1);
        m1 = hi;
        m2 = fmaxf(lo, fmaxf(m2, o2));  // 2nd-max of union
    }
    const float gs = m1 + m2;           // group score of group (lane>>3)

    // ---- select top-4 groups (stable: ties -> lower group index) ----
    float gsj[8];
    #pragma unroll
    for (int j = 0; j < 8; ++j) gsj[j] = __shfl(gs, j * 8);
    const int myg = lane >> 3;
    int rank = 0;
    #pragma unroll
    for (int j = 0; j < 8; ++j)
        rank += (gsj[j] > gs) || (gsj[j] == gs && j < myg);
    const bool sel = rank < TOPK_GROUP;

    // tmp scores: biased score if group selected else 0.0 (matches jnp.where).
    float tv[4];
    #pragma unroll
    for (int j = 0; j < 4; ++j) tv[j] = sel ? sb[j] : 0.0f;

    // ---- top-8 over 256 values: 8x wave argmax (value desc, index asc) ----
    float wk[TOPK];
    int   idk[TOPK];
    float wsum = 0.0f;
    #pragma unroll
    for (int k = 0; k < TOPK; ++k) {
        // local argmax (ascending scan with strict > keeps lowest index on tie)
        float v = tv[0]; int bi = 0;
        #pragma unroll
        for (int j = 1; j < 4; ++j) if (tv[j] > v) { v = tv[j]; bi = j; }
        int idx = lane * 4 + bi;
        // full-wave butterfly argmax; total order (v desc, idx asc) -> all
        // lanes converge to the same global winner.
        #pragma unroll
        for (int d = 1; d < 64; d <<= 1) {
            float ov = __shfl_xor(v, d);
            int   oi = __shfl_xor(idx, d);
            if (ov > v || (ov == v && oi < idx)) { v = ov; idx = oi; }
        }
        idk[k] = idx;
        // owning lane removes the winner (static indexing — no scratch)
        #pragma unroll
        for (int j = 0; j < 4; ++j)
            if (idx == lane * 4 + j) tv[j] = -INFINITY;
        // weight comes from the UNbiased sigmoid score at idx
        const int q = idx & 3;
        float cand = sc[0];
        #pragma unroll
        for (int j = 1; j < 4; ++j) cand = (q == j) ? sc[j] : cand;
        float w = __shfl(cand, idx >> 2);
        wk[k] = w;
        wsum += w;
    }

    if (lane == 0) {
        const float inv = SCALE / wsum;
        float4 w0 = make_float4(wk[0]*inv, wk[1]*inv, wk[2]*inv, wk[3]*inv);
        float4 w1 = make_float4(wk[4]*inv, wk[5]*inv, wk[6]*inv, wk[7]*inv);
        float4 i0 = make_float4((float)idk[0], (float)idk[1], (float)idk[2], (float)idk[3]);
        float4 i1 = make_float4((float)idk[4], (float)idk[5], (float)idk[6], (float)idk[7]);
        *reinterpret_cast<float4*>(out_w  + (size_t)row * TOPK)     = w0;
        *reinterpret_cast<float4*>(out_w  + (size_t)row * TOPK + 4) = w1;
        *reinterpret_cast<float4*>(out_id + (size_t)row * TOPK)     = i0;
        *reinterpret_cast<float4*>(out_id + (size_t)row * TOPK + 4) = i1;
    }
}

extern "C" void kernel_launch(void* const* d_in, const int* in_sizes, int n_in,
                              void* d_out, int out_size, void* d_ws, size_t ws_size,
                              hipStream_t stream) {
    // inputs: [0] hidden_states (UNUSED), [1] router_logits [T,256], [2] correction_bias [256]
    const float* logits = (const float*)d_in[1];
    const float* bias   = (const float*)d_in[2];
    const int T = in_sizes[1] / E;

    float* out    = (float*)d_out;
    float* out_w  = out;                          // [T*8]
    float* out_id = out + (size_t)T * TOPK;       // [T*8]
    float* out_lg = out + (size_t)2 * T * TOPK;   // [T*256]

    // 1 wave per row, 4 waves (256 threads) per block.
    const int rows_per_block = 4;
    const int grid = (T + rows_per_block - 1) / rows_per_block;
    router_topk_kernel<<<grid, 256, 0, stream>>>(logits, bias, out_w, out_id, out_lg, T);
}